// Round 4
// baseline (479.817 us; speedup 1.0000x reference)
//
#include <hip/hip_runtime.h>
#include <hip/hip_bf16.h>
#include <math.h>

#define N_TOTAL 32768
#define E_TOTAL 524288
#define NUM_GRAPHS 64
#define NPG 512
#define EMB 128
#define MAXD 64
#define KTOP 64
#define LATENT 513
#define PPAD 524

typedef __attribute__((ext_vector_type(8))) short bf16x8;
typedef __attribute__((ext_vector_type(4))) float f32x4;

__device__ __forceinline__ unsigned short f2bf(float f) {
    unsigned u = __float_as_uint(f);
    return (unsigned short)((u + 0x7FFFu + ((u >> 16) & 1u)) >> 16);   // RNE
}
__device__ __forceinline__ float bf2f(unsigned short h) {
    return __uint_as_float(((unsigned)h) << 16);
}

// ---------------- setup kernels ----------------

__global__ __launch_bounds__(256) void k_init(int* __restrict__ deg, int* __restrict__ cnt) {
    int i = blockIdx.x * 256 + threadIdx.x;
    if (i < N_TOTAL) { deg[i] = 1; cnt[i] = 0; }   // deg starts at 1 (self loop in src concat)
}

__global__ __launch_bounds__(256) void k_build(const int* __restrict__ ei,
                                               int* __restrict__ deg, int* __restrict__ cnt,
                                               int* __restrict__ adj) {
    int e = blockIdx.x * 256 + threadIdx.x;
    if (e >= E_TOTAL) return;
    int s = ei[e];
    int d = ei[E_TOTAL + e];
    atomicAdd(&deg[s], 1);
    int slot = atomicAdd(&cnt[d], 1);
    if (slot < MAXD) adj[(size_t)d * MAXD + slot] = s;
}

// ---------------- W prep: transpose + bf16 hi/lo split ----------------
// Wc [4][128(k)][128(o)] f32  ->  Wt_hi/Wt_lo [4][128(o)][128(k)] bf16

__global__ __launch_bounds__(256) void k_prep(const float* __restrict__ Wc,
                                              unsigned short* __restrict__ Wth,
                                              unsigned short* __restrict__ Wtl) {
    __shared__ float tile[64][65];
    int b = blockIdx.x;                 // 16 blocks: 4 layers x 4 (64x64) tiles
    int l = b >> 2, t = b & 3;
    int k0 = (t >> 1) * 64, o0 = (t & 1) * 64;
    int lane = threadIdx.x & 63, q = threadIdx.x >> 6;
    const float* Wsrc = Wc + (size_t)l * 16384;
#pragma unroll
    for (int it = 0; it < 16; ++it) {
        int r = it * 4 + q;
        tile[r][lane] = Wsrc[(size_t)(k0 + r) * 128 + o0 + lane];
    }
    __syncthreads();
#pragma unroll
    for (int it = 0; it < 16; ++it) {
        int o = it * 4 + q;
        float v = tile[lane][o];
        unsigned short h = f2bf(v);
        unsigned short lo = f2bf(v - bf2f(h));
        size_t dst = (size_t)l * 16384 + (size_t)(o0 + o) * 128 + k0 + lane;
        Wth[dst] = h; Wtl[dst] = lo;
    }
}

// ---------------- fused layer: gather-agg -> split-bf16 MFMA @W -> tanh ----------------
// Hout[v] = tanh((Sum_{u in in(v)+self} Hin[u]) @ W + (cnt+1)*b) / deg[v])
// If Wl != null (layer 3): also tmp[v] = Hout[v] . Wl + bl  (fused last_lin)

__global__ __launch_bounds__(256) void k_layer(const int* __restrict__ xids,
                                               const float* __restrict__ Hin,
                                               const unsigned short* __restrict__ Wth,
                                               const unsigned short* __restrict__ Wtl,
                                               const float* __restrict__ bvec,
                                               const float* __restrict__ Wl,
                                               const float* __restrict__ bl,
                                               float* __restrict__ tmp,
                                               float* __restrict__ Hout,
                                               const int* __restrict__ adj,
                                               const int* __restrict__ cnt,
                                               const int* __restrict__ deg) {
    __shared__ unsigned char smem[32768];      // A_hi [64 rows][256B] then A_lo
    int tid = threadIdx.x;
    int w = tid >> 6, lane = tid & 63;
    int bid = blockIdx.x;                      // 512 blocks
    int xcd = bid & 7, j = bid >> 3;
    int g = (xcd << 3) + (j >> 3);             // 8 graphs per XCD
    int chunk = j & 7;
    int rowbase = g * NPG + chunk * 64 + w * 16;   // wave-private 16 rows
    const float2* h2 = (const float2*)Hin;

    // ---- gather phase: two rows in flight per iteration ----
    for (int i = 0; i < 16; i += 2) {
        int va = rowbase + i, vb = va + 1;
        int ca = cnt[va]; if (ca > MAXD) ca = MAXD;
        int cb = cnt[vb]; if (cb > MAXD) cb = MAXD;
        const int* Aa = adj + (size_t)va * MAXD;
        const int* Ab = adj + (size_t)vb * MAXD;
        int na = (lane < ca) ? Aa[lane] : 0;
        int nb = (lane < cb) ? Ab[lane] : 0;
        int ia = va, ib = vb;
        if (xids) {                            // layer 0: indices are vocab ids into emb
            na = (lane < ca) ? xids[na] : 0;
            nb = (lane < cb) ? xids[nb] : 0;
            ia = xids[va]; ib = xids[vb];
        }
        float2 sa = h2[(size_t)ia * 64 + lane];
        float2 sb = h2[(size_t)ib * 64 + lane];
        int mx = ca > cb ? ca : cb;
        for (int t = 0; t < mx; ++t) {         // wave-uniform branches
            if (t < ca) { float2 v = h2[(size_t)__shfl(na, t) * 64 + lane]; sa.x += v.x; sa.y += v.y; }
            if (t < cb) { float2 v = h2[(size_t)__shfl(nb, t) * 64 + lane]; sb.x += v.x; sb.y += v.y; }
        }
        // split to bf16 hi/lo, store swizzled (G4: row-major stride-256B would be 16-way conflict)
#pragma unroll
        for (int p = 0; p < 2; ++p) {
            float2 s = p ? sb : sa;
            int r = w * 16 + i + p;
            unsigned short hx = f2bf(s.x), hy = f2bf(s.y);
            unsigned short lx = f2bf(s.x - bf2f(hx)), ly = f2bf(s.y - bf2f(hy));
            int byte = r * 256 + ((lane * 4) ^ ((r & 7) << 4));
            *(unsigned*)(smem + byte)         = (unsigned)hx | ((unsigned)hy << 16);
            *(unsigned*)(smem + 16384 + byte) = (unsigned)lx | ((unsigned)ly << 16);
        }
    }
    __syncthreads();

    // ---- MFMA phase: 16 rows x 128 cols, K=128, split-bf16 (hh + hl + lh) ----
    int r = lane & 15, kb = lane >> 4;
    bf16x8 ah[4], al[4];
#pragma unroll
    for (int ks = 0; ks < 4; ++ks) {
        int byte = (w * 16 + r) * 256 + (((ks * 64 + kb * 16)) ^ ((r & 7) << 4));
        ah[ks] = *(const bf16x8*)(smem + byte);
        al[ks] = *(const bf16x8*)(smem + 16384 + byte);
    }
    float invd[4], cp1[4];
#pragma unroll
    for (int q = 0; q < 4; ++q) {
        int nd = rowbase + kb * 4 + q;
        invd[q] = 1.0f / (float)deg[nd];
        cp1[q]  = (float)(cnt[nd] + 1);
    }
    float ls0 = 0.f, ls1 = 0.f, ls2 = 0.f, ls3 = 0.f;   // fused last_lin partials
    for (int ct = 0; ct < 8; ++ct) {
        const unsigned short* Wh = Wth + (size_t)(ct * 16 + r) * 128;
        const unsigned short* Wo = Wtl + (size_t)(ct * 16 + r) * 128;
        f32x4 a = {0.f, 0.f, 0.f, 0.f};
#pragma unroll
        for (int ks = 0; ks < 4; ++ks) {
            bf16x8 wh = *(const bf16x8*)(Wh + ks * 32 + kb * 8);
            bf16x8 wl = *(const bf16x8*)(Wo + ks * 32 + kb * 8);
            a = __builtin_amdgcn_mfma_f32_16x16x32_bf16(ah[ks], wh, a, 0, 0, 0);
            a = __builtin_amdgcn_mfma_f32_16x16x32_bf16(ah[ks], wl, a, 0, 0, 0);
            a = __builtin_amdgcn_mfma_f32_16x16x32_bf16(al[ks], wh, a, 0, 0, 0);
        }
        float bcol = bvec[ct * 16 + r];
        float wlast = Wl ? Wl[ct * 16 + r] : 0.f;
#pragma unroll
        for (int q = 0; q < 4; ++q) {
            float val = tanhf((a[q] + bcol * cp1[q]) * invd[q]);
            Hout[(size_t)(rowbase + kb * 4 + q) * 128 + ct * 16 + r] = val;
            if (Wl) {
                float z = val * wlast;
                if (q == 0) ls0 += z; else if (q == 1) ls1 += z;
                else if (q == 2) ls2 += z; else ls3 += z;
            }
        }
    }
    if (Wl) {
#pragma unroll
        for (int m = 1; m < 16; m <<= 1) {
            ls0 += __shfl_xor(ls0, m); ls1 += __shfl_xor(ls1, m);
            ls2 += __shfl_xor(ls2, m); ls3 += __shfl_xor(ls3, m);
        }
        if (r == 0) {
            float b0 = bl[0];
            tmp[rowbase + kb * 4 + 0] = ls0 + b0;
            tmp[rowbase + kb * 4 + 1] = ls1 + b0;
            tmp[rowbase + kb * 4 + 2] = ls2 + b0;
            tmp[rowbase + kb * 4 + 3] = ls3 + b0;
        }
    }
}

// ---------------- last aggregation (scalar channel) ----------------

__global__ __launch_bounds__(256) void k_last_agg(const float* __restrict__ tmp,
                                                  const int* __restrict__ adj,
                                                  const int* __restrict__ cnt,
                                                  const int* __restrict__ deg,
                                                  float* __restrict__ lastc) {
    int v = blockIdx.x * 256 + threadIdx.x;
    if (v >= N_TOTAL) return;
    float s = tmp[v];
    int c = cnt[v]; if (c > MAXD) c = MAXD;
    const int* av = adj + (size_t)v * MAXD;
    for (int i = 0; i < c; ++i) s += tmp[av[i]];
    lastc[v] = tanhf(s / (float)deg[v]);
}

// ---------------- sort pool: exact bitonic (val desc, idx asc) ----------------

__global__ __launch_bounds__(256) void k_sort(const float* __restrict__ lastc,
                                              int* __restrict__ topk) {
    __shared__ float v[512];
    __shared__ int ix[512];
    int g = blockIdx.x, tid = threadIdx.x;
    for (int i = tid; i < 512; i += 256) { v[i] = lastc[g * NPG + i]; ix[i] = i; }
    __syncthreads();
    for (int ksz = 2; ksz <= 512; ksz <<= 1) {
        for (int jj = ksz >> 1; jj > 0; jj >>= 1) {
            for (int i = tid; i < 512; i += 256) {
                int p = i ^ jj;
                if (p > i) {
                    float va = v[i], vb = v[p];
                    int ia = ix[i], ib = ix[p];
                    bool b_before_a = (vb > va) || (vb == va && ib < ia);
                    bool up = (i & ksz) == 0;
                    bool sw = up ? b_before_a : !b_before_a;
                    if (sw) { v[i] = vb; v[p] = va; ix[i] = ib; ix[p] = ia; }
                }
            }
            __syncthreads();
        }
    }
    for (int k = tid; k < KTOP; k += 256) topk[g * KTOP + k] = g * NPG + ix[k];
}

// ---------------- conv1 + relu + maxpool: 256 blocks ----------------

__global__ __launch_bounds__(256) void k_conv1(const int* __restrict__ topk,
                                               const float* __restrict__ h0,
                                               const float* __restrict__ h1,
                                               const float* __restrict__ h2,
                                               const float* __restrict__ h3,
                                               const float* __restrict__ lastc,
                                               const float* __restrict__ c1w,
                                               const float* __restrict__ c1b,
                                               float* __restrict__ y1p) {
    __shared__ float P[16][PPAD];
    __shared__ float Y1c[16][16];
    __shared__ int nodes[16];
    int bid = blockIdx.x;
    int g = bid >> 2, cc = bid & 3;
    int tid = threadIdx.x;
    if (tid < 16) nodes[tid] = topk[g * KTOP + cc * 16 + tid];
    __syncthreads();

    {
        int r = tid >> 4, t4 = tid & 15;
        int node = nodes[r];
#pragma unroll
        for (int jj = 0; jj < 8; ++jj) {
            int d = (t4 + 16 * jj) * 4;
            const float* src = (d < 128) ? h0 : (d < 256) ? h1 : (d < 384) ? h2 : h3;
            float4 val = *(const float4*)(src + (size_t)node * 128 + (d & 127));
            *(float4*)&P[r][d] = val;
        }
        if (t4 == 0) P[r][512] = lastc[node];
    }
    __syncthreads();

    int o = tid >> 4, kk = tid & 15;
    const float* w = c1w + (size_t)o * LATENT;
    float a0 = 0.f, a1 = 0.f, a2 = 0.f, a3 = 0.f;
    for (int d = 0; d < 512; d += 4) {
        float4 p = *(const float4*)&P[kk][d];
        a0 = fmaf(p.x, w[d],     a0);
        a1 = fmaf(p.y, w[d + 1], a1);
        a2 = fmaf(p.z, w[d + 2], a2);
        a3 = fmaf(p.w, w[d + 3], a3);
    }
    float s = ((a0 + a1) + (a2 + a3)) + P[kk][512] * w[512] + c1b[o];
    Y1c[o][kk] = fmaxf(s, 0.f);
    __syncthreads();

    if (tid < 128) {
        int oo = tid >> 3, l = tid & 7;
        y1p[(size_t)g * 512 + oo * 32 + cc * 8 + l] = fmaxf(Y1c[oo][2 * l], Y1c[oo][2 * l + 1]);
    }
}

// ---------------- conv2 + dense + softmax: 64 blocks ----------------

__global__ __launch_bounds__(256) void k_tail(const float* __restrict__ y1p,
                                              const float* __restrict__ c2w, const float* __restrict__ c2b,
                                              const float* __restrict__ d1w, const float* __restrict__ d1b,
                                              const float* __restrict__ d2w, const float* __restrict__ d2b,
                                              float* __restrict__ out) {
    __shared__ float Y1P[16][32];
    __shared__ float Y2[32][28];
    __shared__ float H1s[32];
    __shared__ float red[256];
    int g = blockIdx.x, tid = threadIdx.x;

    for (int t = tid; t < 512; t += 256) ((float*)Y1P)[t] = y1p[(size_t)g * 512 + t];
    __syncthreads();

    for (int t = tid; t < 32 * 28; t += 256) {
        int o2 = t / 28, tt = t - o2 * 28;
        float s = c2b[o2];
#pragma unroll
        for (int i = 0; i < 16; ++i)
#pragma unroll
            for (int dt = 0; dt < 5; ++dt)
                s = fmaf(Y1P[i][tt + dt], c2w[o2 * 80 + i * 5 + dt], s);
        Y2[o2][tt] = fmaxf(s, 0.f);
    }
    __syncthreads();

    {
        int jcol = tid >> 3, part = tid & 7;
        float s = 0.f;
        for (int rr = 0; rr < 4; ++rr) {
            int o2 = part * 4 + rr;
            int base = o2 * 28;
            for (int tt = 0; tt < 28; ++tt)
                s = fmaf(Y2[o2][tt], d1w[(size_t)(base + tt) * 32 + jcol], s);
        }
        red[tid] = s;
        __syncthreads();
        if (part == 0) {
            float t = 0.f;
#pragma unroll
            for (int p = 0; p < 8; ++p) t += red[tid + p];
            H1s[jcol] = fmaxf(t + d1b[jcol], 0.f);
        }
        __syncthreads();
    }

    if (tid == 0) {
        float l0 = d2b[0], l1 = d2b[1];
        for (int jc = 0; jc < 32; ++jc) {
            l0 = fmaf(H1s[jc], d2w[jc * 2 + 0], l0);
            l1 = fmaf(H1s[jc], d2w[jc * 2 + 1], l1);
        }
        float m = fmaxf(l0, l1);
        float e0 = expf(l0 - m), e1 = expf(l1 - m);
        float inv = 1.f / (e0 + e1);
        out[g * 2 + 0] = e0 * inv;
        out[g * 2 + 1] = e1 * inv;
    }
}

// ---------------- launch ----------------

extern "C" void kernel_launch(void* const* d_in, const int* in_sizes, int n_in,
                              void* d_out, int out_size, void* d_ws, size_t ws_size,
                              hipStream_t stream) {
    const int*   x    = (const int*)d_in[0];
    const int*   ei   = (const int*)d_in[1];
    const float* emb  = (const float*)d_in[3];
    const float* Wc   = (const float*)d_in[4];
    const float* bc   = (const float*)d_in[5];
    const float* Wl   = (const float*)d_in[6];
    const float* bl   = (const float*)d_in[7];
    const float* c1w  = (const float*)d_in[8];
    const float* c1b  = (const float*)d_in[9];
    const float* c2w  = (const float*)d_in[10];
    const float* c2b  = (const float*)d_in[11];
    const float* d1w  = (const float*)d_in[12];
    const float* d1b  = (const float*)d_in[13];
    const float* d2w  = (const float*)d_in[14];
    const float* d2b  = (const float*)d_in[15];
    float* out = (float*)d_out;

    char* ws = (char*)d_ws;
    int*   deg  = (int*)ws;            ws += (size_t)N_TOTAL * 4;
    int*   cnt  = (int*)ws;            ws += (size_t)N_TOTAL * 4;
    int*   adj  = (int*)ws;            ws += (size_t)N_TOTAL * MAXD * 4;
    float* Hid0 = (float*)ws;          ws += (size_t)N_TOTAL * 128 * 4;
    float* Hid1 = (float*)ws;          ws += (size_t)N_TOTAL * 128 * 4;
    float* Hid2 = (float*)ws;          ws += (size_t)N_TOTAL * 128 * 4;
    float* Hid3 = (float*)ws;          ws += (size_t)N_TOTAL * 128 * 4;
    unsigned short* Wth = (unsigned short*)ws;  ws += (size_t)4 * 128 * 128 * 2;
    unsigned short* Wtl = (unsigned short*)ws;  ws += (size_t)4 * 128 * 128 * 2;
    float* tmp  = (float*)ws;          ws += (size_t)N_TOTAL * 4;
    float* lastc= (float*)ws;          ws += (size_t)N_TOTAL * 4;
    int*   topk = (int*)ws;            ws += (size_t)NUM_GRAPHS * KTOP * 4;
    float* y1p  = (float*)ws;          ws += (size_t)NUM_GRAPHS * 16 * 32 * 4;

    k_init <<<N_TOTAL / 256, 256, 0, stream>>>(deg, cnt);
    k_build<<<E_TOTAL / 256, 256, 0, stream>>>(ei, deg, cnt, adj);
    k_prep <<<16, 256, 0, stream>>>(Wc, Wth, Wtl);

    float* Hids[4] = {Hid0, Hid1, Hid2, Hid3};
    for (int l = 0; l < 4; ++l) {
        const int*   xl  = (l == 0) ? x : nullptr;
        const float* hin = (l == 0) ? emb : Hids[l - 1];
        const float* wl  = (l == 3) ? Wl : nullptr;
        const float* blp = (l == 3) ? bl : nullptr;
        float*       tp  = (l == 3) ? tmp : nullptr;
        k_layer<<<512, 256, 0, stream>>>(xl, hin,
                                         Wth + (size_t)l * 16384, Wtl + (size_t)l * 16384,
                                         bc + (size_t)l * 128, wl, blp, tp,
                                         Hids[l], adj, cnt, deg);
    }
    k_last_agg<<<N_TOTAL / 256, 256, 0, stream>>>(tmp, adj, cnt, deg, lastc);
    k_sort<<<NUM_GRAPHS, 256, 0, stream>>>(lastc, topk);
    k_conv1<<<NUM_GRAPHS * 4, 256, 0, stream>>>(topk, Hid0, Hid1, Hid2, Hid3, lastc, c1w, c1b, y1p);
    k_tail<<<NUM_GRAPHS, 256, 0, stream>>>(y1p, c2w, c2b, d1w, d1b, d2w, d2b, out);
}

// Round 5
// 370.917 us; speedup vs baseline: 1.2936x; 1.2936x over previous
//
#include <hip/hip_runtime.h>
#include <hip/hip_bf16.h>
#include <math.h>

#define N_TOTAL 32768
#define E_TOTAL 524288
#define NUM_GRAPHS 64
#define NPG 512
#define EMB 128
#define MAXD 64
#define KTOP 64
#define LATENT 513
#define PPAD 524

typedef __attribute__((ext_vector_type(8))) short bf16x8;
typedef __attribute__((ext_vector_type(4))) float f32x4;

__device__ __forceinline__ unsigned short f2bf(float f) {
    unsigned u = __float_as_uint(f);
    return (unsigned short)((u + 0x7FFFu + ((u >> 16) & 1u)) >> 16);   // RNE
}
__device__ __forceinline__ float bf2f(unsigned short h) {
    return __uint_as_float(((unsigned)h) << 16);
}

// ---------------- setup kernels ----------------

__global__ __launch_bounds__(256) void k_init(int* __restrict__ deg, int* __restrict__ cnt) {
    int i = blockIdx.x * 256 + threadIdx.x;
    if (i < N_TOTAL) { deg[i] = 1; cnt[i] = 0; }   // deg starts at 1 (self loop in src concat)
}

__global__ __launch_bounds__(256) void k_build(const int* __restrict__ ei,
                                               int* __restrict__ deg, int* __restrict__ cnt,
                                               int* __restrict__ adj) {
    int e = blockIdx.x * 256 + threadIdx.x;
    if (e >= E_TOTAL) return;
    int s = ei[e];
    int d = ei[E_TOTAL + e];
    atomicAdd(&deg[s], 1);
    int slot = atomicAdd(&cnt[d], 1);
    if (slot < MAXD) adj[(size_t)d * MAXD + slot] = s;
}

// ---------------- W prep: transpose + bf16 hi/lo split ----------------
// Wc [4][128(k)][128(o)] f32  ->  Wt_hi/Wt_lo [4][128(o)][128(k)] bf16

__global__ __launch_bounds__(256) void k_prep(const float* __restrict__ Wc,
                                              unsigned short* __restrict__ Wth,
                                              unsigned short* __restrict__ Wtl) {
    __shared__ float tile[64][65];
    int b = blockIdx.x;                 // 16 blocks: 4 layers x 4 (64x64) tiles
    int l = b >> 2, t = b & 3;
    int k0 = (t >> 1) * 64, o0 = (t & 1) * 64;
    int lane = threadIdx.x & 63, q = threadIdx.x >> 6;
    const float* Wsrc = Wc + (size_t)l * 16384;
#pragma unroll
    for (int it = 0; it < 16; ++it) {
        int r = it * 4 + q;
        tile[r][lane] = Wsrc[(size_t)(k0 + r) * 128 + o0 + lane];
    }
    __syncthreads();
#pragma unroll
    for (int it = 0; it < 16; ++it) {
        int o = it * 4 + q;
        float v = tile[lane][o];
        unsigned short h = f2bf(v);
        unsigned short lo = f2bf(v - bf2f(h));
        size_t dst = (size_t)l * 16384 + (size_t)(o0 + o) * 128 + k0 + lane;
        Wth[dst] = h; Wtl[dst] = lo;
    }
}

// ---------------- fused layer: gather-agg -> split-bf16 MFMA @W -> tanh ----------------
// 2048 blocks; block = 16 rows; 4 waves: each gathers 4 rows (4 in flight),
// then each wave computes 2 of 8 column tiles from the shared LDS A-tile.

__global__ __launch_bounds__(256) void k_layer(const int* __restrict__ xids,
                                               const float* __restrict__ Hin,
                                               const unsigned short* __restrict__ Wth,
                                               const unsigned short* __restrict__ Wtl,
                                               const float* __restrict__ bvec,
                                               const float* __restrict__ Wl,
                                               const float* __restrict__ bl,
                                               float* __restrict__ tmp,
                                               float* __restrict__ Hout,
                                               const int* __restrict__ adj,
                                               const int* __restrict__ cnt,
                                               const int* __restrict__ deg) {
    __shared__ unsigned char smem[8192];       // A_hi [16 rows][256B] then A_lo at +4096
    __shared__ float lsum[16];
    int tid = threadIdx.x;
    int w = tid >> 6, lane = tid & 63;
    int bid = blockIdx.x;                      // 2048 blocks
    int xcd = bid & 7, j = bid >> 3;           // j: 0..255
    int g = (xcd << 3) + (j >> 5);             // 8 graphs per XCD -> L2 residency
    int chunk = j & 31;
    int rowbase = g * NPG + chunk * 16;        // block's 16 rows
    int wrow = rowbase + w * 4;                // wave's 4 rows
    const float2* h2 = (const float2*)Hin;

    // ---- gather phase: 4 rows in flight ----
    int   c4[4]; int nb4[4]; float2 s4[4];
#pragma unroll
    for (int p = 0; p < 4; ++p) {
        int v = wrow + p;
        int c = cnt[v]; if (c > MAXD) c = MAXD;
        c4[p] = c;
        const int* av = adj + (size_t)v * MAXD;
        int nb = (lane < c) ? av[lane] : 0;
        int iv = v;
        if (xids) {                            // layer 0: map node -> vocab id into emb
            nb = (lane < c) ? xids[nb] : 0;
            iv = xids[v];
        }
        nb4[p] = nb;
        s4[p] = h2[(size_t)iv * 64 + lane];    // self loop
    }
    int mx = max(max(c4[0], c4[1]), max(c4[2], c4[3]));
    for (int t = 0; t < mx; ++t) {             // wave-uniform predicates; 4 loads in flight
#pragma unroll
        for (int p = 0; p < 4; ++p) {
            if (t < c4[p]) {
                float2 v = h2[(size_t)__shfl(nb4[p], t) * 64 + lane];
                s4[p].x += v.x; s4[p].y += v.y;
            }
        }
    }
    // split to bf16 hi/lo, store XOR-swizzled (row-major 256B rows would be bank-conflicted)
#pragma unroll
    for (int p = 0; p < 4; ++p) {
        int r = w * 4 + p;
        unsigned short hx = f2bf(s4[p].x), hy = f2bf(s4[p].y);
        unsigned short lx = f2bf(s4[p].x - bf2f(hx)), ly = f2bf(s4[p].y - bf2f(hy));
        int byte = r * 256 + ((lane * 4) ^ ((r & 7) << 4));
        *(unsigned*)(smem + byte)        = (unsigned)hx | ((unsigned)hy << 16);
        *(unsigned*)(smem + 4096 + byte) = (unsigned)lx | ((unsigned)ly << 16);
    }
    if (tid < 16) lsum[tid] = 0.f;
    __syncthreads();

    // ---- MFMA phase: 16 rows x 128 cols, K=128, split-bf16 (hh + hl + lh) ----
    int r = lane & 15, kb = lane >> 4;
    bf16x8 ah[4], al[4];
#pragma unroll
    for (int ks = 0; ks < 4; ++ks) {
        int byte = r * 256 + ((ks * 64 + kb * 16) ^ ((r & 7) << 4));
        ah[ks] = *(const bf16x8*)(smem + byte);
        al[ks] = *(const bf16x8*)(smem + 4096 + byte);
    }
    float invd[4], cp1[4];
#pragma unroll
    for (int q = 0; q < 4; ++q) {
        int nd = rowbase + kb * 4 + q;
        invd[q] = 1.0f / (float)deg[nd];
        cp1[q]  = (float)(cnt[nd] + 1);
    }
    float z[4] = {0.f, 0.f, 0.f, 0.f};         // fused last_lin partials (layer 3)
#pragma unroll
    for (int cti = 0; cti < 2; ++cti) {
        int ct = w * 2 + cti;
        const unsigned short* Wh = Wth + (size_t)(ct * 16 + r) * 128;
        const unsigned short* Wo = Wtl + (size_t)(ct * 16 + r) * 128;
        f32x4 a = {0.f, 0.f, 0.f, 0.f};
#pragma unroll
        for (int ks = 0; ks < 4; ++ks) {
            bf16x8 wh = *(const bf16x8*)(Wh + ks * 32 + kb * 8);
            bf16x8 wl = *(const bf16x8*)(Wo + ks * 32 + kb * 8);
            a = __builtin_amdgcn_mfma_f32_16x16x32_bf16(ah[ks], wh, a, 0, 0, 0);
            a = __builtin_amdgcn_mfma_f32_16x16x32_bf16(ah[ks], wl, a, 0, 0, 0);
            a = __builtin_amdgcn_mfma_f32_16x16x32_bf16(al[ks], wh, a, 0, 0, 0);
        }
        float bcol = bvec[ct * 16 + r];
        float wlast = Wl ? Wl[ct * 16 + r] : 0.f;
#pragma unroll
        for (int q = 0; q < 4; ++q) {
            float val = tanhf((a[q] + bcol * cp1[q]) * invd[q]);
            Hout[(size_t)(rowbase + kb * 4 + q) * 128 + ct * 16 + r] = val;
            z[q] = fmaf(val, wlast, z[q]);
        }
    }
    if (Wl) {
#pragma unroll
        for (int m = 1; m < 16; m <<= 1) {     // reduce over r within each 16-lane group
            z[0] += __shfl_xor(z[0], m); z[1] += __shfl_xor(z[1], m);
            z[2] += __shfl_xor(z[2], m); z[3] += __shfl_xor(z[3], m);
        }
        if (r == 0) {
#pragma unroll
            for (int q = 0; q < 4; ++q) atomicAdd(&lsum[kb * 4 + q], z[q]);
        }
        __syncthreads();
        if (tid < 16) tmp[rowbase + tid] = lsum[tid] + bl[0];
    }
}

// ---------------- last aggregation (scalar channel) ----------------

__global__ __launch_bounds__(256) void k_last_agg(const float* __restrict__ tmp,
                                                  const int* __restrict__ adj,
                                                  const int* __restrict__ cnt,
                                                  const int* __restrict__ deg,
                                                  float* __restrict__ lastc) {
    int v = blockIdx.x * 256 + threadIdx.x;
    if (v >= N_TOTAL) return;
    float s = tmp[v];
    int c = cnt[v]; if (c > MAXD) c = MAXD;
    const int* av = adj + (size_t)v * MAXD;
    for (int i = 0; i < c; ++i) s += tmp[av[i]];
    lastc[v] = tanhf(s / (float)deg[v]);
}

// ---------------- sort pool: exact bitonic (val desc, idx asc) ----------------

__global__ __launch_bounds__(256) void k_sort(const float* __restrict__ lastc,
                                              int* __restrict__ topk) {
    __shared__ float v[512];
    __shared__ int ix[512];
    int g = blockIdx.x, tid = threadIdx.x;
    for (int i = tid; i < 512; i += 256) { v[i] = lastc[g * NPG + i]; ix[i] = i; }
    __syncthreads();
    for (int ksz = 2; ksz <= 512; ksz <<= 1) {
        for (int jj = ksz >> 1; jj > 0; jj >>= 1) {
            for (int i = tid; i < 512; i += 256) {
                int p = i ^ jj;
                if (p > i) {
                    float va = v[i], vb = v[p];
                    int ia = ix[i], ib = ix[p];
                    bool b_before_a = (vb > va) || (vb == va && ib < ia);
                    bool up = (i & ksz) == 0;
                    bool sw = up ? b_before_a : !b_before_a;
                    if (sw) { v[i] = vb; v[p] = va; ix[i] = ib; ix[p] = ia; }
                }
            }
            __syncthreads();
        }
    }
    for (int k = tid; k < KTOP; k += 256) topk[g * KTOP + k] = g * NPG + ix[k];
}

// ---------------- conv1 + relu + maxpool: 256 blocks ----------------

__global__ __launch_bounds__(256) void k_conv1(const int* __restrict__ topk,
                                               const float* __restrict__ h0,
                                               const float* __restrict__ h1,
                                               const float* __restrict__ h2,
                                               const float* __restrict__ h3,
                                               const float* __restrict__ lastc,
                                               const float* __restrict__ c1w,
                                               const float* __restrict__ c1b,
                                               float* __restrict__ y1p) {
    __shared__ float P[16][PPAD];
    __shared__ float Y1c[16][16];
    __shared__ int nodes[16];
    int bid = blockIdx.x;
    int g = bid >> 2, cc = bid & 3;
    int tid = threadIdx.x;
    if (tid < 16) nodes[tid] = topk[g * KTOP + cc * 16 + tid];
    __syncthreads();

    {
        int r = tid >> 4, t4 = tid & 15;
        int node = nodes[r];
#pragma unroll
        for (int jj = 0; jj < 8; ++jj) {
            int d = (t4 + 16 * jj) * 4;
            const float* src = (d < 128) ? h0 : (d < 256) ? h1 : (d < 384) ? h2 : h3;
            float4 val = *(const float4*)(src + (size_t)node * 128 + (d & 127));
            *(float4*)&P[r][d] = val;
        }
        if (t4 == 0) P[r][512] = lastc[node];
    }
    __syncthreads();

    int o = tid >> 4, kk = tid & 15;
    const float* w = c1w + (size_t)o * LATENT;
    float a0 = 0.f, a1 = 0.f, a2 = 0.f, a3 = 0.f;
    for (int d = 0; d < 512; d += 4) {
        float4 p = *(const float4*)&P[kk][d];
        a0 = fmaf(p.x, w[d],     a0);
        a1 = fmaf(p.y, w[d + 1], a1);
        a2 = fmaf(p.z, w[d + 2], a2);
        a3 = fmaf(p.w, w[d + 3], a3);
    }
    float s = ((a0 + a1) + (a2 + a3)) + P[kk][512] * w[512] + c1b[o];
    Y1c[o][kk] = fmaxf(s, 0.f);
    __syncthreads();

    if (tid < 128) {
        int oo = tid >> 3, l = tid & 7;
        y1p[(size_t)g * 512 + oo * 32 + cc * 8 + l] = fmaxf(Y1c[oo][2 * l], Y1c[oo][2 * l + 1]);
    }
}

// ---------------- conv2 + dense + softmax: 64 blocks ----------------

__global__ __launch_bounds__(256) void k_tail(const float* __restrict__ y1p,
                                              const float* __restrict__ c2w, const float* __restrict__ c2b,
                                              const float* __restrict__ d1w, const float* __restrict__ d1b,
                                              const float* __restrict__ d2w, const float* __restrict__ d2b,
                                              float* __restrict__ out) {
    __shared__ float Y1P[16][32];
    __shared__ float Y2[32][28];
    __shared__ float H1s[32];
    __shared__ float red[256];
    int g = blockIdx.x, tid = threadIdx.x;

    for (int t = tid; t < 512; t += 256) ((float*)Y1P)[t] = y1p[(size_t)g * 512 + t];
    __syncthreads();

    for (int t = tid; t < 32 * 28; t += 256) {
        int o2 = t / 28, tt = t - o2 * 28;
        float s = c2b[o2];
#pragma unroll
        for (int i = 0; i < 16; ++i)
#pragma unroll
            for (int dt = 0; dt < 5; ++dt)
                s = fmaf(Y1P[i][tt + dt], c2w[o2 * 80 + i * 5 + dt], s);
        Y2[o2][tt] = fmaxf(s, 0.f);
    }
    __syncthreads();

    {
        int jcol = tid >> 3, part = tid & 7;
        float s = 0.f;
        for (int rr = 0; rr < 4; ++rr) {
            int o2 = part * 4 + rr;
            int base = o2 * 28;
            for (int tt = 0; tt < 28; ++tt)
                s = fmaf(Y2[o2][tt], d1w[(size_t)(base + tt) * 32 + jcol], s);
        }
        red[tid] = s;
        __syncthreads();
        if (part == 0) {
            float t = 0.f;
#pragma unroll
            for (int p = 0; p < 8; ++p) t += red[tid + p];
            H1s[jcol] = fmaxf(t + d1b[jcol], 0.f);
        }
        __syncthreads();
    }

    if (tid == 0) {
        float l0 = d2b[0], l1 = d2b[1];
        for (int jc = 0; jc < 32; ++jc) {
            l0 = fmaf(H1s[jc], d2w[jc * 2 + 0], l0);
            l1 = fmaf(H1s[jc], d2w[jc * 2 + 1], l1);
        }
        float m = fmaxf(l0, l1);
        float e0 = expf(l0 - m), e1 = expf(l1 - m);
        float inv = 1.f / (e0 + e1);
        out[g * 2 + 0] = e0 * inv;
        out[g * 2 + 1] = e1 * inv;
    }
}

// ---------------- launch ----------------

extern "C" void kernel_launch(void* const* d_in, const int* in_sizes, int n_in,
                              void* d_out, int out_size, void* d_ws, size_t ws_size,
                              hipStream_t stream) {
    const int*   x    = (const int*)d_in[0];
    const int*   ei   = (const int*)d_in[1];
    const float* emb  = (const float*)d_in[3];
    const float* Wc   = (const float*)d_in[4];
    const float* bc   = (const float*)d_in[5];
    const float* Wl   = (const float*)d_in[6];
    const float* bl   = (const float*)d_in[7];
    const float* c1w  = (const float*)d_in[8];
    const float* c1b  = (const float*)d_in[9];
    const float* c2w  = (const float*)d_in[10];
    const float* c2b  = (const float*)d_in[11];
    const float* d1w  = (const float*)d_in[12];
    const float* d1b  = (const float*)d_in[13];
    const float* d2w  = (const float*)d_in[14];
    const float* d2b  = (const float*)d_in[15];
    float* out = (float*)d_out;

    char* ws = (char*)d_ws;
    int*   deg  = (int*)ws;            ws += (size_t)N_TOTAL * 4;
    int*   cnt  = (int*)ws;            ws += (size_t)N_TOTAL * 4;
    int*   adj  = (int*)ws;            ws += (size_t)N_TOTAL * MAXD * 4;
    float* Hid0 = (float*)ws;          ws += (size_t)N_TOTAL * 128 * 4;
    float* Hid1 = (float*)ws;          ws += (size_t)N_TOTAL * 128 * 4;
    float* Hid2 = (float*)ws;          ws += (size_t)N_TOTAL * 128 * 4;
    float* Hid3 = (float*)ws;          ws += (size_t)N_TOTAL * 128 * 4;
    unsigned short* Wth = (unsigned short*)ws;  ws += (size_t)4 * 128 * 128 * 2;
    unsigned short* Wtl = (unsigned short*)ws;  ws += (size_t)4 * 128 * 128 * 2;
    float* tmp  = (float*)ws;          ws += (size_t)N_TOTAL * 4;
    float* lastc= (float*)ws;          ws += (size_t)N_TOTAL * 4;
    int*   topk = (int*)ws;            ws += (size_t)NUM_GRAPHS * KTOP * 4;
    float* y1p  = (float*)ws;          ws += (size_t)NUM_GRAPHS * 16 * 32 * 4;

    k_init <<<N_TOTAL / 256, 256, 0, stream>>>(deg, cnt);
    k_build<<<E_TOTAL / 256, 256, 0, stream>>>(ei, deg, cnt, adj);
    k_prep <<<16, 256, 0, stream>>>(Wc, Wth, Wtl);

    float* Hids[4] = {Hid0, Hid1, Hid2, Hid3};
    for (int l = 0; l < 4; ++l) {
        const int*   xl  = (l == 0) ? x : nullptr;
        const float* hin = (l == 0) ? emb : Hids[l - 1];
        const float* wl  = (l == 3) ? Wl : nullptr;
        const float* blp = (l == 3) ? bl : nullptr;
        float*       tp  = (l == 3) ? tmp : nullptr;
        k_layer<<<N_TOTAL / 16, 256, 0, stream>>>(xl, hin,
                                                  Wth + (size_t)l * 16384, Wtl + (size_t)l * 16384,
                                                  bc + (size_t)l * 128, wl, blp, tp,
                                                  Hids[l], adj, cnt, deg);
    }
    k_last_agg<<<N_TOTAL / 256, 256, 0, stream>>>(tmp, adj, cnt, deg, lastc);
    k_sort<<<NUM_GRAPHS, 256, 0, stream>>>(lastc, topk);
    k_conv1<<<NUM_GRAPHS * 4, 256, 0, stream>>>(topk, Hid0, Hid1, Hid2, Hid3, lastc, c1w, c1b, y1p);
    k_tail<<<NUM_GRAPHS, 256, 0, stream>>>(y1p, c2w, c2b, d1w, d1b, d2w, d2b, out);
}

// Round 6
// 365.194 us; speedup vs baseline: 1.3139x; 1.0157x over previous
//
#include <hip/hip_runtime.h>
#include <hip/hip_bf16.h>
#include <math.h>

#define N_TOTAL 32768
#define E_TOTAL 524288
#define NUM_GRAPHS 64
#define NPG 512
#define EMB 128
#define MAXD 64
#define KTOP 64
#define LATENT 513
#define PPAD 524

typedef __attribute__((ext_vector_type(8))) short bf16x8;
typedef __attribute__((ext_vector_type(4))) float f32x4;

__device__ __forceinline__ unsigned short f2bf(float f) {
    unsigned u = __float_as_uint(f);
    return (unsigned short)((u + 0x7FFFu + ((u >> 16) & 1u)) >> 16);   // RNE
}
__device__ __forceinline__ float bf2f(unsigned short h) {
    return __uint_as_float(((unsigned)h) << 16);
}

// ---------------- setup kernels ----------------

__global__ __launch_bounds__(256) void k_init(int* __restrict__ deg, int* __restrict__ cnt) {
    int i = blockIdx.x * 256 + threadIdx.x;
    if (i < N_TOTAL) { deg[i] = 1; cnt[i] = 0; }   // deg starts at 1 (self loop in src concat)
}

__global__ __launch_bounds__(256) void k_build(const int* __restrict__ ei,
                                               int* __restrict__ deg, int* __restrict__ cnt,
                                               int* __restrict__ adj) {
    int e = blockIdx.x * 256 + threadIdx.x;
    if (e >= E_TOTAL) return;
    int s = ei[e];
    int d = ei[E_TOTAL + e];
    atomicAdd(&deg[s], 1);
    int slot = atomicAdd(&cnt[d], 1);
    if (slot < MAXD) adj[(size_t)d * MAXD + slot] = s;
}

// ---------------- W prep: transpose + bf16 hi/lo split ----------------
// Wc [4][128(k)][128(o)] f32  ->  Wt_hi/Wt_lo [4][128(o)][128(k)] bf16

__global__ __launch_bounds__(256) void k_prep(const float* __restrict__ Wc,
                                              unsigned short* __restrict__ Wth,
                                              unsigned short* __restrict__ Wtl) {
    __shared__ float tile[64][65];
    int b = blockIdx.x;                 // 16 blocks: 4 layers x 4 (64x64) tiles
    int l = b >> 2, t = b & 3;
    int k0 = (t >> 1) * 64, o0 = (t & 1) * 64;
    int lane = threadIdx.x & 63, q = threadIdx.x >> 6;
    const float* Wsrc = Wc + (size_t)l * 16384;
#pragma unroll
    for (int it = 0; it < 16; ++it) {
        int r = it * 4 + q;
        tile[r][lane] = Wsrc[(size_t)(k0 + r) * 128 + o0 + lane];
    }
    __syncthreads();
#pragma unroll
    for (int it = 0; it < 16; ++it) {
        int o = it * 4 + q;
        float v = tile[lane][o];
        unsigned short h = f2bf(v);
        unsigned short lo = f2bf(v - bf2f(h));
        size_t dst = (size_t)l * 16384 + (size_t)(o0 + o) * 128 + k0 + lane;
        Wth[dst] = h; Wtl[dst] = lo;
    }
}

// ---------------- fused layer: gather-agg -> split-bf16 MFMA @W -> tanh ----------------
// 2048 blocks; block = 16 rows; 4 waves: each gathers 4 rows with a 4-deep
// unrolled neighbor loop (16 loads in flight), then computes 2 of 8 col tiles.

__global__ __launch_bounds__(256) void k_layer(const int* __restrict__ xids,
                                               const float* __restrict__ Hin,
                                               const unsigned short* __restrict__ Wth,
                                               const unsigned short* __restrict__ Wtl,
                                               const float* __restrict__ bvec,
                                               const float* __restrict__ Wl,
                                               const float* __restrict__ bl,
                                               float* __restrict__ tmp,
                                               float* __restrict__ Hout,
                                               const int* __restrict__ adj,
                                               const int* __restrict__ cnt,
                                               const int* __restrict__ deg) {
    __shared__ unsigned char smem[8192];       // A_hi [16 rows][256B] then A_lo at +4096
    __shared__ float lsum[16];
    int tid = threadIdx.x;
    int w = tid >> 6, lane = tid & 63;
    int bid = blockIdx.x;                      // 2048 blocks
    int xcd = bid & 7, j = bid >> 3;           // j: 0..255
    int g = (xcd << 3) + (j >> 5);             // 8 graphs per XCD -> L2 residency
    int chunk = j & 31;
    int rowbase = g * NPG + chunk * 16;        // block's 16 rows
    int wrow = rowbase + w * 4;                // wave's 4 rows
    const float2* h2 = (const float2*)Hin;

    // ---- gather phase: 4 rows x 4-deep unroll = 16 loads in flight ----
    int c4[4]; int nb4[4];
    float2 s0[4], s1[4], s2[4], s3[4];
#pragma unroll
    for (int p = 0; p < 4; ++p) {
        int v = wrow + p;
        int c = cnt[v]; if (c > MAXD) c = MAXD;
        c4[p] = c;
        const int* av = adj + (size_t)v * MAXD;
        int nb = (lane < c) ? av[lane] : 0;
        int iv = v;
        if (xids) {                            // layer 0: map node -> vocab id into emb
            nb = (lane < c) ? xids[nb] : 0;
            iv = xids[v];
        }
        nb4[p] = nb;
        s0[p] = h2[(size_t)iv * 64 + lane];    // self loop
        s1[p] = make_float2(0.f, 0.f);
        s2[p] = make_float2(0.f, 0.f);
        s3[p] = make_float2(0.f, 0.f);
    }
    int mx = max(max(c4[0], c4[1]), max(c4[2], c4[3]));
    for (int t = 0; t < mx; t += 4) {          // all guards wave-uniform
#pragma unroll
        for (int p = 0; p < 4; ++p) if (t < c4[p]) {
            float2 v = h2[(size_t)__shfl(nb4[p], t) * 64 + lane];
            s0[p].x += v.x; s0[p].y += v.y;
        }
#pragma unroll
        for (int p = 0; p < 4; ++p) if (t + 1 < c4[p]) {
            float2 v = h2[(size_t)__shfl(nb4[p], t + 1) * 64 + lane];
            s1[p].x += v.x; s1[p].y += v.y;
        }
#pragma unroll
        for (int p = 0; p < 4; ++p) if (t + 2 < c4[p]) {
            float2 v = h2[(size_t)__shfl(nb4[p], t + 2) * 64 + lane];
            s2[p].x += v.x; s2[p].y += v.y;
        }
#pragma unroll
        for (int p = 0; p < 4; ++p) if (t + 3 < c4[p]) {
            float2 v = h2[(size_t)__shfl(nb4[p], t + 3) * 64 + lane];
            s3[p].x += v.x; s3[p].y += v.y;
        }
    }
    // combine chains; split to bf16 hi/lo; XOR-swizzled LDS store
#pragma unroll
    for (int p = 0; p < 4; ++p) {
        float2 s;
        s.x = (s0[p].x + s1[p].x) + (s2[p].x + s3[p].x);
        s.y = (s0[p].y + s1[p].y) + (s2[p].y + s3[p].y);
        int r = w * 4 + p;
        unsigned short hx = f2bf(s.x), hy = f2bf(s.y);
        unsigned short lx = f2bf(s.x - bf2f(hx)), ly = f2bf(s.y - bf2f(hy));
        int byte = r * 256 + ((lane * 4) ^ ((r & 7) << 4));
        *(unsigned*)(smem + byte)        = (unsigned)hx | ((unsigned)hy << 16);
        *(unsigned*)(smem + 4096 + byte) = (unsigned)lx | ((unsigned)ly << 16);
    }
    if (tid < 16) lsum[tid] = 0.f;
    __syncthreads();

    // ---- MFMA phase: 16 rows x 128 cols, K=128, split-bf16 (hh + hl + lh) ----
    int r = lane & 15, kb = lane >> 4;
    bf16x8 ah[4], al[4];
#pragma unroll
    for (int ks = 0; ks < 4; ++ks) {
        int byte = r * 256 + ((ks * 64 + kb * 16) ^ ((r & 7) << 4));
        ah[ks] = *(const bf16x8*)(smem + byte);
        al[ks] = *(const bf16x8*)(smem + 4096 + byte);
    }
    float invd[4], cp1[4];
#pragma unroll
    for (int q = 0; q < 4; ++q) {
        int nd = rowbase + kb * 4 + q;
        invd[q] = 1.0f / (float)deg[nd];
        cp1[q]  = (float)(cnt[nd] + 1);
    }
    float z[4] = {0.f, 0.f, 0.f, 0.f};         // fused last_lin partials (layer 3)
#pragma unroll
    for (int cti = 0; cti < 2; ++cti) {
        int ct = w * 2 + cti;
        const unsigned short* Wh = Wth + (size_t)(ct * 16 + r) * 128;
        const unsigned short* Wo = Wtl + (size_t)(ct * 16 + r) * 128;
        f32x4 a = {0.f, 0.f, 0.f, 0.f};
#pragma unroll
        for (int ks = 0; ks < 4; ++ks) {
            bf16x8 wh = *(const bf16x8*)(Wh + ks * 32 + kb * 8);
            bf16x8 wl = *(const bf16x8*)(Wo + ks * 32 + kb * 8);
            a = __builtin_amdgcn_mfma_f32_16x16x32_bf16(ah[ks], wh, a, 0, 0, 0);
            a = __builtin_amdgcn_mfma_f32_16x16x32_bf16(ah[ks], wl, a, 0, 0, 0);
            a = __builtin_amdgcn_mfma_f32_16x16x32_bf16(al[ks], wh, a, 0, 0, 0);
        }
        float bcol = bvec[ct * 16 + r];
        float wlast = Wl ? Wl[ct * 16 + r] : 0.f;
#pragma unroll
        for (int q = 0; q < 4; ++q) {
            float val = tanhf((a[q] + bcol * cp1[q]) * invd[q]);
            Hout[(size_t)(rowbase + kb * 4 + q) * 128 + ct * 16 + r] = val;
            z[q] = fmaf(val, wlast, z[q]);
        }
    }
    if (Wl) {
#pragma unroll
        for (int m = 1; m < 16; m <<= 1) {     // reduce over r within each 16-lane group
            z[0] += __shfl_xor(z[0], m); z[1] += __shfl_xor(z[1], m);
            z[2] += __shfl_xor(z[2], m); z[3] += __shfl_xor(z[3], m);
        }
        if (r == 0) {
#pragma unroll
            for (int q = 0; q < 4; ++q) atomicAdd(&lsum[kb * 4 + q], z[q]);
        }
        __syncthreads();
        if (tid < 16) tmp[rowbase + tid] = lsum[tid] + bl[0];
    }
}

// ---------------- sort pool (fused last-channel aggregation + exact bitonic sort) --------

__global__ __launch_bounds__(256) void k_sort(const float* __restrict__ tmp,
                                              const int* __restrict__ adj,
                                              const int* __restrict__ cnt,
                                              const int* __restrict__ deg,
                                              float* __restrict__ lastc,
                                              int* __restrict__ topk) {
    __shared__ float v[512];
    __shared__ int ix[512];
    int g = blockIdx.x, tid = threadIdx.x;
    for (int i = tid; i < 512; i += 256) {
        int node = g * NPG + i;
        float s = tmp[node];
        int c = cnt[node]; if (c > MAXD) c = MAXD;
        const int* av = adj + (size_t)node * MAXD;
#pragma unroll 4
        for (int q = 0; q < c; ++q) s += tmp[av[q]];
        float val = tanhf(s / (float)deg[node]);
        lastc[node] = val;                    // k_conv1 still reads this
        v[i] = val; ix[i] = i;
    }
    __syncthreads();
    for (int ksz = 2; ksz <= 512; ksz <<= 1) {
        for (int jj = ksz >> 1; jj > 0; jj >>= 1) {
            for (int i = tid; i < 512; i += 256) {
                int p = i ^ jj;
                if (p > i) {
                    float va = v[i], vb = v[p];
                    int ia = ix[i], ib = ix[p];
                    bool b_before_a = (vb > va) || (vb == va && ib < ia);
                    bool up = (i & ksz) == 0;
                    bool sw = up ? b_before_a : !b_before_a;
                    if (sw) { v[i] = vb; v[p] = va; ix[i] = ib; ix[p] = ia; }
                }
            }
            __syncthreads();
        }
    }
    for (int k = tid; k < KTOP; k += 256) topk[g * KTOP + k] = g * NPG + ix[k];
}

// ---------------- conv1 + relu + maxpool: 256 blocks ----------------

__global__ __launch_bounds__(256) void k_conv1(const int* __restrict__ topk,
                                               const float* __restrict__ h0,
                                               const float* __restrict__ h1,
                                               const float* __restrict__ h2,
                                               const float* __restrict__ h3,
                                               const float* __restrict__ lastc,
                                               const float* __restrict__ c1w,
                                               const float* __restrict__ c1b,
                                               float* __restrict__ y1p) {
    __shared__ float P[16][PPAD];
    __shared__ float Y1c[16][16];
    __shared__ int nodes[16];
    int bid = blockIdx.x;
    int g = bid >> 2, cc = bid & 3;
    int tid = threadIdx.x;
    if (tid < 16) nodes[tid] = topk[g * KTOP + cc * 16 + tid];
    __syncthreads();

    {
        int r = tid >> 4, t4 = tid & 15;
        int node = nodes[r];
#pragma unroll
        for (int jj = 0; jj < 8; ++jj) {
            int d = (t4 + 16 * jj) * 4;
            const float* src = (d < 128) ? h0 : (d < 256) ? h1 : (d < 384) ? h2 : h3;
            float4 val = *(const float4*)(src + (size_t)node * 128 + (d & 127));
            *(float4*)&P[r][d] = val;
        }
        if (t4 == 0) P[r][512] = lastc[node];
    }
    __syncthreads();

    int o = tid >> 4, kk = tid & 15;
    const float* w = c1w + (size_t)o * LATENT;
    float a0 = 0.f, a1 = 0.f, a2 = 0.f, a3 = 0.f;
    for (int d = 0; d < 512; d += 4) {
        float4 p = *(const float4*)&P[kk][d];
        a0 = fmaf(p.x, w[d],     a0);
        a1 = fmaf(p.y, w[d + 1], a1);
        a2 = fmaf(p.z, w[d + 2], a2);
        a3 = fmaf(p.w, w[d + 3], a3);
    }
    float s = ((a0 + a1) + (a2 + a3)) + P[kk][512] * w[512] + c1b[o];
    Y1c[o][kk] = fmaxf(s, 0.f);
    __syncthreads();

    if (tid < 128) {
        int oo = tid >> 3, l = tid & 7;
        y1p[(size_t)g * 512 + oo * 32 + cc * 8 + l] = fmaxf(Y1c[oo][2 * l], Y1c[oo][2 * l + 1]);
    }
}

// ---------------- conv2 + dense + softmax: 64 blocks ----------------

__global__ __launch_bounds__(256) void k_tail(const float* __restrict__ y1p,
                                              const float* __restrict__ c2w, const float* __restrict__ c2b,
                                              const float* __restrict__ d1w, const float* __restrict__ d1b,
                                              const float* __restrict__ d2w, const float* __restrict__ d2b,
                                              float* __restrict__ out) {
    __shared__ float Y1P[16][32];
    __shared__ float Y2[32][28];
    __shared__ float H1s[32];
    __shared__ float red[256];
    int g = blockIdx.x, tid = threadIdx.x;

    for (int t = tid; t < 512; t += 256) ((float*)Y1P)[t] = y1p[(size_t)g * 512 + t];
    __syncthreads();

    for (int t = tid; t < 32 * 28; t += 256) {
        int o2 = t / 28, tt = t - o2 * 28;
        float s = c2b[o2];
#pragma unroll
        for (int i = 0; i < 16; ++i)
#pragma unroll
            for (int dt = 0; dt < 5; ++dt)
                s = fmaf(Y1P[i][tt + dt], c2w[o2 * 80 + i * 5 + dt], s);
        Y2[o2][tt] = fmaxf(s, 0.f);
    }
    __syncthreads();

    {
        int jcol = tid >> 3, part = tid & 7;
        float s = 0.f;
        for (int rr = 0; rr < 4; ++rr) {
            int o2 = part * 4 + rr;
            int base = o2 * 28;
            for (int tt = 0; tt < 28; ++tt)
                s = fmaf(Y2[o2][tt], d1w[(size_t)(base + tt) * 32 + jcol], s);
        }
        red[tid] = s;
        __syncthreads();
        if (part == 0) {
            float t = 0.f;
#pragma unroll
            for (int p = 0; p < 8; ++p) t += red[tid + p];
            H1s[jcol] = fmaxf(t + d1b[jcol], 0.f);
        }
        __syncthreads();
    }

    if (tid == 0) {
        float l0 = d2b[0], l1 = d2b[1];
        for (int jc = 0; jc < 32; ++jc) {
            l0 = fmaf(H1s[jc], d2w[jc * 2 + 0], l0);
            l1 = fmaf(H1s[jc], d2w[jc * 2 + 1], l1);
        }
        float m = fmaxf(l0, l1);
        float e0 = expf(l0 - m), e1 = expf(l1 - m);
        float inv = 1.f / (e0 + e1);
        out[g * 2 + 0] = e0 * inv;
        out[g * 2 + 1] = e1 * inv;
    }
}

// ---------------- launch ----------------

extern "C" void kernel_launch(void* const* d_in, const int* in_sizes, int n_in,
                              void* d_out, int out_size, void* d_ws, size_t ws_size,
                              hipStream_t stream) {
    const int*   x    = (const int*)d_in[0];
    const int*   ei   = (const int*)d_in[1];
    const float* emb  = (const float*)d_in[3];
    const float* Wc   = (const float*)d_in[4];
    const float* bc   = (const float*)d_in[5];
    const float* Wl   = (const float*)d_in[6];
    const float* bl   = (const float*)d_in[7];
    const float* c1w  = (const float*)d_in[8];
    const float* c1b  = (const float*)d_in[9];
    const float* c2w  = (const float*)d_in[10];
    const float* c2b  = (const float*)d_in[11];
    const float* d1w  = (const float*)d_in[12];
    const float* d1b  = (const float*)d_in[13];
    const float* d2w  = (const float*)d_in[14];
    const float* d2b  = (const float*)d_in[15];
    float* out = (float*)d_out;

    char* ws = (char*)d_ws;
    int*   deg  = (int*)ws;            ws += (size_t)N_TOTAL * 4;
    int*   cnt  = (int*)ws;            ws += (size_t)N_TOTAL * 4;
    int*   adj  = (int*)ws;            ws += (size_t)N_TOTAL * MAXD * 4;
    float* Hid0 = (float*)ws;          ws += (size_t)N_TOTAL * 128 * 4;
    float* Hid1 = (float*)ws;          ws += (size_t)N_TOTAL * 128 * 4;
    float* Hid2 = (float*)ws;          ws += (size_t)N_TOTAL * 128 * 4;
    float* Hid3 = (float*)ws;          ws += (size_t)N_TOTAL * 128 * 4;
    unsigned short* Wth = (unsigned short*)ws;  ws += (size_t)4 * 128 * 128 * 2;
    unsigned short* Wtl = (unsigned short*)ws;  ws += (size_t)4 * 128 * 128 * 2;
    float* tmp  = (float*)ws;          ws += (size_t)N_TOTAL * 4;
    float* lastc= (float*)ws;          ws += (size_t)N_TOTAL * 4;
    int*   topk = (int*)ws;            ws += (size_t)NUM_GRAPHS * KTOP * 4;
    float* y1p  = (float*)ws;          ws += (size_t)NUM_GRAPHS * 16 * 32 * 4;

    k_init <<<N_TOTAL / 256, 256, 0, stream>>>(deg, cnt);
    k_build<<<E_TOTAL / 256, 256, 0, stream>>>(ei, deg, cnt, adj);
    k_prep <<<16, 256, 0, stream>>>(Wc, Wth, Wtl);

    float* Hids[4] = {Hid0, Hid1, Hid2, Hid3};
    for (int l = 0; l < 4; ++l) {
        const int*   xl  = (l == 0) ? x : nullptr;
        const float* hin = (l == 0) ? emb : Hids[l - 1];
        const float* wl  = (l == 3) ? Wl : nullptr;
        const float* blp = (l == 3) ? bl : nullptr;
        float*       tp  = (l == 3) ? tmp : nullptr;
        k_layer<<<N_TOTAL / 16, 256, 0, stream>>>(xl, hin,
                                                  Wth + (size_t)l * 16384, Wtl + (size_t)l * 16384,
                                                  bc + (size_t)l * 128, wl, blp, tp,
                                                  Hids[l], adj, cnt, deg);
    }
    k_sort<<<NUM_GRAPHS, 256, 0, stream>>>(tmp, adj, cnt, deg, lastc, topk);
    k_conv1<<<NUM_GRAPHS * 4, 256, 0, stream>>>(topk, Hid0, Hid1, Hid2, Hid3, lastc, c1w, c1b, y1p);
    k_tail<<<NUM_GRAPHS, 256, 0, stream>>>(y1p, c2w, c2b, d1w, d1b, d2w, d2b, out);
}

// Round 7
// 342.076 us; speedup vs baseline: 1.4027x; 1.0676x over previous
//
#include <hip/hip_runtime.h>
#include <hip/hip_bf16.h>
#include <math.h>

#define N_TOTAL 32768
#define E_TOTAL 524288
#define NUM_GRAPHS 64
#define NPG 512
#define EMB 128
#define MAXD 64
#define KTOP 64
#define LATENT 513
#define PPAD 524

typedef __attribute__((ext_vector_type(8))) short bf16x8;
typedef __attribute__((ext_vector_type(4))) float f32x4;

__device__ __forceinline__ unsigned short f2bf(float f) {
    unsigned u = __float_as_uint(f);
    return (unsigned short)((u + 0x7FFFu + ((u >> 16) & 1u)) >> 16);   // RNE
}
__device__ __forceinline__ float bf2f(unsigned short h) {
    return __uint_as_float(((unsigned)h) << 16);
}

// ---------------- setup kernels ----------------

__global__ __launch_bounds__(256) void k_init(int* __restrict__ deg, int* __restrict__ cnt) {
    int i = blockIdx.x * 256 + threadIdx.x;
    if (i < N_TOTAL) { deg[i] = 1; cnt[i] = 0; }   // deg starts at 1 (self loop in src concat)
}

__global__ __launch_bounds__(256) void k_build(const int* __restrict__ ei,
                                               int* __restrict__ deg, int* __restrict__ cnt,
                                               int* __restrict__ adj) {
    int e = blockIdx.x * 256 + threadIdx.x;
    if (e >= E_TOTAL) return;
    int s = ei[e];
    int d = ei[E_TOTAL + e];
    atomicAdd(&deg[s], 1);
    int slot = atomicAdd(&cnt[d], 1);
    if (slot < MAXD) adj[(size_t)d * MAXD + slot] = s;
}

// ---------------- W prep: transpose + bf16 hi/lo split ----------------
// Wc [4][128(k)][128(o)] f32  ->  Wt_hi/Wt_lo [4][128(o)][128(k)] bf16

__global__ __launch_bounds__(256) void k_prep(const float* __restrict__ Wc,
                                              unsigned short* __restrict__ Wth,
                                              unsigned short* __restrict__ Wtl) {
    __shared__ float tile[64][65];
    int b = blockIdx.x;                 // 16 blocks: 4 layers x 4 (64x64) tiles
    int l = b >> 2, t = b & 3;
    int k0 = (t >> 1) * 64, o0 = (t & 1) * 64;
    int lane = threadIdx.x & 63, q = threadIdx.x >> 6;
    const float* Wsrc = Wc + (size_t)l * 16384;
#pragma unroll
    for (int it = 0; it < 16; ++it) {
        int r = it * 4 + q;
        tile[r][lane] = Wsrc[(size_t)(k0 + r) * 128 + o0 + lane];
    }
    __syncthreads();
#pragma unroll
    for (int it = 0; it < 16; ++it) {
        int o = it * 4 + q;
        float v = tile[lane][o];
        unsigned short h = f2bf(v);
        unsigned short lo = f2bf(v - bf2f(h));
        size_t dst = (size_t)l * 16384 + (size_t)(o0 + o) * 128 + k0 + lane;
        Wth[dst] = h; Wtl[dst] = lo;
    }
}

// ---------------- fused layer: gather-agg -> split-bf16 MFMA @W -> tanh ----------------
// 2048 blocks; block = 16 rows; 4 waves x 4 rows. BRANCHLESS gather: loads are
// unconditional (lane-table guarantees valid index), accumulate is masked by a
// {0,1} multiplier -> all loads pipeline under one vmcnt region.

__global__ __launch_bounds__(256) void k_layer(const int* __restrict__ xids,
                                               const float* __restrict__ Hin,
                                               const unsigned short* __restrict__ Wth,
                                               const unsigned short* __restrict__ Wtl,
                                               const float* __restrict__ bvec,
                                               const float* __restrict__ Wl,
                                               const float* __restrict__ bl,
                                               float* __restrict__ tmp,
                                               float* __restrict__ Hout,
                                               const int* __restrict__ adj,
                                               const int* __restrict__ cnt,
                                               const int* __restrict__ deg) {
    __shared__ unsigned char smem[8192];       // A_hi [16 rows][256B] then A_lo at +4096
    __shared__ float lsum[16];
    int tid = threadIdx.x;
    int w = tid >> 6, lane = tid & 63;
    int bid = blockIdx.x;                      // 2048 blocks
    int xcd = bid & 7, j = bid >> 3;           // j: 0..255
    int g = (xcd << 3) + (j >> 5);             // 8 graphs per XCD -> L2 residency
    int chunk = j & 31;
    int rowbase = g * NPG + chunk * 16;        // block's 16 rows
    int wrow = rowbase + w * 4;                // wave's 4 rows
    const float2* h2 = (const float2*)Hin;

    // ---- gather setup ----
    int c4[4]; int nb4[4];
    float2 s0[4], s1[4];
#pragma unroll
    for (int p = 0; p < 4; ++p) {
        int v = wrow + p;
        int c = cnt[v]; if (c > MAXD) c = MAXD;
        c4[p] = c;
        const int* av = adj + (size_t)v * MAXD;
        int nb = (lane < c) ? av[lane] : 0;    // valid row index for EVERY lane
        int iv = v;
        if (xids) {                            // layer 0: map node -> vocab id into emb
            nb = (lane < c) ? xids[nb] : 0;
            iv = xids[v];
        }
        nb4[p] = nb;
        s0[p] = h2[(size_t)iv * 64 + lane];    // self loop
        s1[p] = make_float2(0.f, 0.f);
    }
    int mx = max(max(c4[0], c4[1]), max(c4[2], c4[3]));

    // ---- branchless gather: 8 unconditional loads per iteration, masked FMA ----
    for (int t = 0; t < mx; t += 2) {
        float2 v0[4], v1[4];
        float m0[4], m1[4];
        int t1 = (t + 1) & 63;                 // valid shfl lane even when t+1==mx
#pragma unroll
        for (int p = 0; p < 4; ++p) {
            v0[p] = h2[(size_t)__shfl(nb4[p], t)  * 64 + lane];
            v1[p] = h2[(size_t)__shfl(nb4[p], t1) * 64 + lane];
            m0[p] = (t     < c4[p]) ? 1.f : 0.f;
            m1[p] = (t + 1 < c4[p]) ? 1.f : 0.f;
        }
#pragma unroll
        for (int p = 0; p < 4; ++p) {
            s0[p].x = fmaf(m0[p], v0[p].x, s0[p].x);
            s0[p].y = fmaf(m0[p], v0[p].y, s0[p].y);
            s1[p].x = fmaf(m1[p], v1[p].x, s1[p].x);
            s1[p].y = fmaf(m1[p], v1[p].y, s1[p].y);
        }
    }
    // combine chains; split to bf16 hi/lo; XOR-swizzled LDS store
#pragma unroll
    for (int p = 0; p < 4; ++p) {
        float2 s;
        s.x = s0[p].x + s1[p].x;
        s.y = s0[p].y + s1[p].y;
        int r = w * 4 + p;
        unsigned short hx = f2bf(s.x), hy = f2bf(s.y);
        unsigned short lx = f2bf(s.x - bf2f(hx)), ly = f2bf(s.y - bf2f(hy));
        int byte = r * 256 + ((lane * 4) ^ ((r & 7) << 4));
        *(unsigned*)(smem + byte)        = (unsigned)hx | ((unsigned)hy << 16);
        *(unsigned*)(smem + 4096 + byte) = (unsigned)lx | ((unsigned)ly << 16);
    }
    if (tid < 16) lsum[tid] = 0.f;
    __syncthreads();

    // ---- MFMA phase: 16 rows x 128 cols, K=128, split-bf16 (hh + hl + lh) ----
    int r = lane & 15, kb = lane >> 4;
    bf16x8 ah[4], al[4];
#pragma unroll
    for (int ks = 0; ks < 4; ++ks) {
        int byte = r * 256 + ((ks * 64 + kb * 16) ^ ((r & 7) << 4));
        ah[ks] = *(const bf16x8*)(smem + byte);
        al[ks] = *(const bf16x8*)(smem + 4096 + byte);
    }
    float invd[4], cp1[4];
#pragma unroll
    for (int q = 0; q < 4; ++q) {
        int nd = rowbase + kb * 4 + q;
        invd[q] = 1.0f / (float)deg[nd];
        cp1[q]  = (float)(cnt[nd] + 1);
    }
    float z[4] = {0.f, 0.f, 0.f, 0.f};         // fused last_lin partials (layer 3)
#pragma unroll
    for (int cti = 0; cti < 2; ++cti) {
        int ct = w * 2 + cti;
        const unsigned short* Wh = Wth + (size_t)(ct * 16 + r) * 128;
        const unsigned short* Wo = Wtl + (size_t)(ct * 16 + r) * 128;
        f32x4 a = {0.f, 0.f, 0.f, 0.f};
#pragma unroll
        for (int ks = 0; ks < 4; ++ks) {
            bf16x8 wh = *(const bf16x8*)(Wh + ks * 32 + kb * 8);
            bf16x8 wl = *(const bf16x8*)(Wo + ks * 32 + kb * 8);
            a = __builtin_amdgcn_mfma_f32_16x16x32_bf16(ah[ks], wh, a, 0, 0, 0);
            a = __builtin_amdgcn_mfma_f32_16x16x32_bf16(ah[ks], wl, a, 0, 0, 0);
            a = __builtin_amdgcn_mfma_f32_16x16x32_bf16(al[ks], wh, a, 0, 0, 0);
        }
        float bcol = bvec[ct * 16 + r];
        float wlast = Wl ? Wl[ct * 16 + r] : 0.f;
#pragma unroll
        for (int q = 0; q < 4; ++q) {
            float val = tanhf((a[q] + bcol * cp1[q]) * invd[q]);
            Hout[(size_t)(rowbase + kb * 4 + q) * 128 + ct * 16 + r] = val;
            z[q] = fmaf(val, wlast, z[q]);
        }
    }
    if (Wl) {
#pragma unroll
        for (int m = 1; m < 16; m <<= 1) {     // reduce over r within each 16-lane group
            z[0] += __shfl_xor(z[0], m); z[1] += __shfl_xor(z[1], m);
            z[2] += __shfl_xor(z[2], m); z[3] += __shfl_xor(z[3], m);
        }
        if (r == 0) {
#pragma unroll
            for (int q = 0; q < 4; ++q) atomicAdd(&lsum[kb * 4 + q], z[q]);
        }
        __syncthreads();
        if (tid < 16) tmp[rowbase + tid] = lsum[tid] + bl[0];
    }
}

// ---------------- sort pool (fused last-channel aggregation + exact bitonic sort) --------

__global__ __launch_bounds__(256) void k_sort(const float* __restrict__ tmp,
                                              const int* __restrict__ adj,
                                              const int* __restrict__ cnt,
                                              const int* __restrict__ deg,
                                              float* __restrict__ lastc,
                                              int* __restrict__ topk) {
    __shared__ float v[512];
    __shared__ int ix[512];
    int g = blockIdx.x, tid = threadIdx.x;
    for (int i = tid; i < 512; i += 256) {
        int node = g * NPG + i;
        float s = tmp[node];
        int c = cnt[node]; if (c > MAXD) c = MAXD;
        const int* av = adj + (size_t)node * MAXD;
#pragma unroll 4
        for (int q = 0; q < c; ++q) s += tmp[av[q]];
        float val = tanhf(s / (float)deg[node]);
        lastc[node] = val;                    // k_conv1 still reads this
        v[i] = val; ix[i] = i;
    }
    __syncthreads();
    for (int ksz = 2; ksz <= 512; ksz <<= 1) {
        for (int jj = ksz >> 1; jj > 0; jj >>= 1) {
            for (int i = tid; i < 512; i += 256) {
                int p = i ^ jj;
                if (p > i) {
                    float va = v[i], vb = v[p];
                    int ia = ix[i], ib = ix[p];
                    bool b_before_a = (vb > va) || (vb == va && ib < ia);
                    bool up = (i & ksz) == 0;
                    bool sw = up ? b_before_a : !b_before_a;
                    if (sw) { v[i] = vb; v[p] = va; ix[i] = ib; ix[p] = ia; }
                }
            }
            __syncthreads();
        }
    }
    for (int k = tid; k < KTOP; k += 256) topk[g * KTOP + k] = g * NPG + ix[k];
}

// ---------------- conv1 + relu + maxpool: 256 blocks ----------------

__global__ __launch_bounds__(256) void k_conv1(const int* __restrict__ topk,
                                               const float* __restrict__ h0,
                                               const float* __restrict__ h1,
                                               const float* __restrict__ h2,
                                               const float* __restrict__ h3,
                                               const float* __restrict__ lastc,
                                               const float* __restrict__ c1w,
                                               const float* __restrict__ c1b,
                                               float* __restrict__ y1p) {
    __shared__ float P[16][PPAD];
    __shared__ float Y1c[16][16];
    __shared__ int nodes[16];
    int bid = blockIdx.x;
    int g = bid >> 2, cc = bid & 3;
    int tid = threadIdx.x;
    if (tid < 16) nodes[tid] = topk[g * KTOP + cc * 16 + tid];
    __syncthreads();

    {
        int r = tid >> 4, t4 = tid & 15;
        int node = nodes[r];
#pragma unroll
        for (int jj = 0; jj < 8; ++jj) {
            int d = (t4 + 16 * jj) * 4;
            const float* src = (d < 128) ? h0 : (d < 256) ? h1 : (d < 384) ? h2 : h3;
            float4 val = *(const float4*)(src + (size_t)node * 128 + (d & 127));
            *(float4*)&P[r][d] = val;
        }
        if (t4 == 0) P[r][512] = lastc[node];
    }
    __syncthreads();

    int o = tid >> 4, kk = tid & 15;
    const float* w = c1w + (size_t)o * LATENT;
    float a0 = 0.f, a1 = 0.f, a2 = 0.f, a3 = 0.f;
    for (int d = 0; d < 512; d += 4) {
        float4 p = *(const float4*)&P[kk][d];
        a0 = fmaf(p.x, w[d],     a0);
        a1 = fmaf(p.y, w[d + 1], a1);
        a2 = fmaf(p.z, w[d + 2], a2);
        a3 = fmaf(p.w, w[d + 3], a3);
    }
    float s = ((a0 + a1) + (a2 + a3)) + P[kk][512] * w[512] + c1b[o];
    Y1c[o][kk] = fmaxf(s, 0.f);
    __syncthreads();

    if (tid < 128) {
        int oo = tid >> 3, l = tid & 7;
        y1p[(size_t)g * 512 + oo * 32 + cc * 8 + l] = fmaxf(Y1c[oo][2 * l], Y1c[oo][2 * l + 1]);
    }
}

// ---------------- conv2 + dense + softmax: 64 blocks ----------------

__global__ __launch_bounds__(256) void k_tail(const float* __restrict__ y1p,
                                              const float* __restrict__ c2w, const float* __restrict__ c2b,
                                              const float* __restrict__ d1w, const float* __restrict__ d1b,
                                              const float* __restrict__ d2w, const float* __restrict__ d2b,
                                              float* __restrict__ out) {
    __shared__ float Y1P[16][32];
    __shared__ float Y2[32][28];
    __shared__ float H1s[32];
    __shared__ float red[256];
    int g = blockIdx.x, tid = threadIdx.x;

    for (int t = tid; t < 512; t += 256) ((float*)Y1P)[t] = y1p[(size_t)g * 512 + t];
    __syncthreads();

    for (int t = tid; t < 32 * 28; t += 256) {
        int o2 = t / 28, tt = t - o2 * 28;
        float s = c2b[o2];
#pragma unroll
        for (int i = 0; i < 16; ++i)
#pragma unroll
            for (int dt = 0; dt < 5; ++dt)
                s = fmaf(Y1P[i][tt + dt], c2w[o2 * 80 + i * 5 + dt], s);
        Y2[o2][tt] = fmaxf(s, 0.f);
    }
    __syncthreads();

    {
        int jcol = tid >> 3, part = tid & 7;
        float s = 0.f;
        for (int rr = 0; rr < 4; ++rr) {
            int o2 = part * 4 + rr;
            int base = o2 * 28;
            for (int tt = 0; tt < 28; ++tt)
                s = fmaf(Y2[o2][tt], d1w[(size_t)(base + tt) * 32 + jcol], s);
        }
        red[tid] = s;
        __syncthreads();
        if (part == 0) {
            float t = 0.f;
#pragma unroll
            for (int p = 0; p < 8; ++p) t += red[tid + p];
            H1s[jcol] = fmaxf(t + d1b[jcol], 0.f);
        }
        __syncthreads();
    }

    if (tid == 0) {
        float l0 = d2b[0], l1 = d2b[1];
        for (int jc = 0; jc < 32; ++jc) {
            l0 = fmaf(H1s[jc], d2w[jc * 2 + 0], l0);
            l1 = fmaf(H1s[jc], d2w[jc * 2 + 1], l1);
        }
        float m = fmaxf(l0, l1);
        float e0 = expf(l0 - m), e1 = expf(l1 - m);
        float inv = 1.f / (e0 + e1);
        out[g * 2 + 0] = e0 * inv;
        out[g * 2 + 1] = e1 * inv;
    }
}

// ---------------- launch ----------------

extern "C" void kernel_launch(void* const* d_in, const int* in_sizes, int n_in,
                              void* d_out, int out_size, void* d_ws, size_t ws_size,
                              hipStream_t stream) {
    const int*   x    = (const int*)d_in[0];
    const int*   ei   = (const int*)d_in[1];
    const float* emb  = (const float*)d_in[3];
    const float* Wc   = (const float*)d_in[4];
    const float* bc   = (const float*)d_in[5];
    const float* Wl   = (const float*)d_in[6];
    const float* bl   = (const float*)d_in[7];
    const float* c1w  = (const float*)d_in[8];
    const float* c1b  = (const float*)d_in[9];
    const float* c2w  = (const float*)d_in[10];
    const float* c2b  = (const float*)d_in[11];
    const float* d1w  = (const float*)d_in[12];
    const float* d1b  = (const float*)d_in[13];
    const float* d2w  = (const float*)d_in[14];
    const float* d2b  = (const float*)d_in[15];
    float* out = (float*)d_out;

    char* ws = (char*)d_ws;
    int*   deg  = (int*)ws;            ws += (size_t)N_TOTAL * 4;
    int*   cnt  = (int*)ws;            ws += (size_t)N_TOTAL * 4;
    int*   adj  = (int*)ws;            ws += (size_t)N_TOTAL * MAXD * 4;
    float* Hid0 = (float*)ws;          ws += (size_t)N_TOTAL * 128 * 4;
    float* Hid1 = (float*)ws;          ws += (size_t)N_TOTAL * 128 * 4;
    float* Hid2 = (float*)ws;          ws += (size_t)N_TOTAL * 128 * 4;
    float* Hid3 = (float*)ws;          ws += (size_t)N_TOTAL * 128 * 4;
    unsigned short* Wth = (unsigned short*)ws;  ws += (size_t)4 * 128 * 128 * 2;
    unsigned short* Wtl = (unsigned short*)ws;  ws += (size_t)4 * 128 * 128 * 2;
    float* tmp  = (float*)ws;          ws += (size_t)N_TOTAL * 4;
    float* lastc= (float*)ws;          ws += (size_t)N_TOTAL * 4;
    int*   topk = (int*)ws;            ws += (size_t)NUM_GRAPHS * KTOP * 4;
    float* y1p  = (float*)ws;          ws += (size_t)NUM_GRAPHS * 16 * 32 * 4;

    k_init <<<N_TOTAL / 256, 256, 0, stream>>>(deg, cnt);
    k_build<<<E_TOTAL / 256, 256, 0, stream>>>(ei, deg, cnt, adj);
    k_prep <<<16, 256, 0, stream>>>(Wc, Wth, Wtl);

    float* Hids[4] = {Hid0, Hid1, Hid2, Hid3};
    for (int l = 0; l < 4; ++l) {
        const int*   xl  = (l == 0) ? x : nullptr;
        const float* hin = (l == 0) ? emb : Hids[l - 1];
        const float* wl  = (l == 3) ? Wl : nullptr;
        const float* blp = (l == 3) ? bl : nullptr;
        float*       tp  = (l == 3) ? tmp : nullptr;
        k_layer<<<N_TOTAL / 16, 256, 0, stream>>>(xl, hin,
                                                  Wth + (size_t)l * 16384, Wtl + (size_t)l * 16384,
                                                  bc + (size_t)l * 128, wl, blp, tp,
                                                  Hids[l], adj, cnt, deg);
    }
    k_sort<<<NUM_GRAPHS, 256, 0, stream>>>(tmp, adj, cnt, deg, lastc, topk);
    k_conv1<<<NUM_GRAPHS * 4, 256, 0, stream>>>(topk, Hid0, Hid1, Hid2, Hid3, lastc, c1w, c1b, y1p);
    k_tail<<<NUM_GRAPHS, 256, 0, stream>>>(y1p, c2w, c2b, d1w, d1b, d2w, d2b, out);
}